// Round 3
// 8509.054 us; speedup vs baseline: 1.5769x; 1.5769x over previous
//
#include <hip/hip_runtime.h>
#include <hip/hip_bf16.h>
#include <math.h>

// Bidir attention, B=8 N=2048 D=1024 topk=16. Inputs fp32, output fp32.
// Top-16 min gap over 32768 rows ~2e-6 => selection needs fp64-class logits.
// Round-2 post-mortem: f64 MFMA fragment layout unverified -> wrong Y (absmax 0.275).
// Round 3: Y back to PROVEN fp64 VALU GEMM (round-0 numerics), with the measured
// 4-way LDS bank conflict fixed via strided microtile (row=ty+16i, col=tx+16j:
// B-reads hit 16 consecutive doubles, stores fully coalesced). Scheme:
//   M  = Wq Wk^T        fp64 VALU GEMM (proven round-0 kernel, untouched)
//   Y  = X  M           fp64 VALU GEMM (proven structure, conflict-free microtile)
//                       + bf16 h/l split epilogue
//   Z~ = Y_split X^T/32 bf16 3-term split MFMA (fp32; zmax/denominator/candidates only)
//   V  = X Wv           bf16 3-term split MFMA (linear, tolerant)
//   topk: top-24 candidates by Z~, EXACT fp64 rescore z = Y_fp64 . X / 32,
//         exact top-16 + fp64 weights (round-0-proven selection semantics).
//
// Workspace (60 MB peak, 64 MB proven safe):
//   M fp64        @ 0   (8 MB)  once
//   Wvh/Wvl bf16  @ 8/10 (2+2)  once
//   Xsh/Xsl bf16  @ 12/16 (4+4) per direction (split of the "other" X)
//   Yd fp64       @ 20 (16 MB)  per direction
//   Yh/Yl bf16    @ 36/40 (4+4) per direction; V fp32 (8 MB) overlays @36 after Z~
//   Z fp32        @ 44 (16 MB)

#define SEQ 2048
#define DIMD 1024
#define NCAND 24

typedef __bf16 bf16x8 __attribute__((ext_vector_type(8)));
typedef float f32x4 __attribute__((ext_vector_type(4)));

__device__ __forceinline__ void split1(float x, unsigned short& h, unsigned short& l)
{
    __hip_bfloat16 hb = __float2bfloat16(x);          // RN
    float hf = __bfloat162float(hb);
    __hip_bfloat16 lb = __float2bfloat16(x - hf);
    h = *reinterpret_cast<unsigned short*>(&hb);
    l = *reinterpret_cast<unsigned short*>(&lb);
}

// ---------------- M = Wq * Wk^T (NT, fp32 in, fp64 acc+store) — proven round-0, untouched ----------------
__global__ __launch_bounds__(256) void k_gemm_m(const float* __restrict__ W,
                                                double* __restrict__ M)
{
    __shared__ double As[16][65];
    __shared__ double Bs[16][65];
    const int tid = threadIdx.x;
    const int tx = tid & 15, ty = tid >> 4;
    const int m0 = blockIdx.x * 64, n0 = blockIdx.y * 64;
    const int lr = tid >> 2;
    const int lk = (tid & 3) * 4;
    double acc[4][4] = {};
    for (int k0 = 0; k0 < 1024; k0 += 16) {
        float4 a = *(const float4*)(W + (size_t)(m0 + lr) * 3072 + k0 + lk);
        As[lk+0][lr] = a.x; As[lk+1][lr] = a.y; As[lk+2][lr] = a.z; As[lk+3][lr] = a.w;
        float4 b = *(const float4*)(W + (size_t)(n0 + lr) * 3072 + 1024 + k0 + lk);
        Bs[lk+0][lr] = b.x; Bs[lk+1][lr] = b.y; Bs[lk+2][lr] = b.z; Bs[lk+3][lr] = b.w;
        __syncthreads();
        #pragma unroll
        for (int kk = 0; kk < 16; ++kk) {
            double av[4], bv[4];
            #pragma unroll
            for (int i = 0; i < 4; ++i) av[i] = As[kk][ty*4+i];
            #pragma unroll
            for (int j = 0; j < 4; ++j) bv[j] = Bs[kk][tx*4+j];
            #pragma unroll
            for (int i = 0; i < 4; ++i)
                #pragma unroll
                for (int j = 0; j < 4; ++j)
                    acc[i][j] = fma(av[i], bv[j], acc[i][j]);
        }
        __syncthreads();
    }
    #pragma unroll
    for (int i = 0; i < 4; ++i)
        #pragma unroll
        for (int j = 0; j < 4; ++j)
            M[(size_t)(m0 + ty*4 + i) * 1024 + n0 + tx*4 + j] = acc[i][j];
}

// ------------- Y = X * M (NN, fp32 A, fp64 B, fp64 acc), proven structure;
// strided microtile: conflict-free B-reads + coalesced stores. + bf16 split epilogue.
__global__ __launch_bounds__(256) void k_gemm_y64(const float* __restrict__ X,
                                                  const double* __restrict__ M,
                                                  double* __restrict__ Yd,
                                                  unsigned short* __restrict__ Yh,
                                                  unsigned short* __restrict__ Yl)
{
    __shared__ double As[16][65];
    __shared__ double Bs[16][65];
    const int tid = threadIdx.x;
    const int tx = tid & 15, ty = tid >> 4;
    const int m0 = blockIdx.x * 64, n0 = blockIdx.y * 64;
    const int lr = tid >> 2;         // 0..63
    const int lk = (tid & 3) * 4;    // 0,4,8,12
    const int bk = tid >> 4;         // 0..15
    const int bn = (tid & 15) * 4;   // 0..60
    double acc[4][4] = {};
    for (int k0 = 0; k0 < 1024; k0 += 16) {
        float4 a = *(const float4*)(X + (size_t)(m0 + lr) * 1024 + k0 + lk);
        As[lk+0][lr] = a.x; As[lk+1][lr] = a.y; As[lk+2][lr] = a.z; As[lk+3][lr] = a.w;
        const double* pb = M + (size_t)(k0 + bk) * 1024 + n0 + bn;
        double2 b01 = *(const double2*)pb;
        double2 b23 = *(const double2*)(pb + 2);
        Bs[bk][bn+0] = b01.x; Bs[bk][bn+1] = b01.y; Bs[bk][bn+2] = b23.x; Bs[bk][bn+3] = b23.y;
        __syncthreads();
        #pragma unroll
        for (int kk = 0; kk < 16; ++kk) {
            double av[4], bv[4];
            #pragma unroll
            for (int i = 0; i < 4; ++i) av[i] = As[kk][ty + 16*i];   // broadcast, conflict-free
            #pragma unroll
            for (int j = 0; j < 4; ++j) bv[j] = Bs[kk][tx + 16*j];   // consecutive, conflict-free
            #pragma unroll
            for (int i = 0; i < 4; ++i)
                #pragma unroll
                for (int j = 0; j < 4; ++j)
                    acc[i][j] = fma(av[i], bv[j], acc[i][j]);
        }
        __syncthreads();
    }
    #pragma unroll
    for (int i = 0; i < 4; ++i)
        #pragma unroll
        for (int j = 0; j < 4; ++j) {
            const double y = acc[i][j];
            const size_t o = (size_t)(m0 + ty + 16*i) * 1024 + n0 + tx + 16*j;
            Yd[o] = y;
            float yf = (float)y;
            __hip_bfloat16 hb = __float2bfloat16(yf);
            float hf = __bfloat162float(hb);
            __hip_bfloat16 lb = __float2bfloat16((float)(y - (double)hf));
            Yh[o] = *reinterpret_cast<unsigned short*>(&hb);
            Yl[o] = *reinterpret_cast<unsigned short*>(&lb);
        }
}

// ---------------- Wv^T split: Th/Tl[n][c] = split(W[c][2048+n]) ----------------
__global__ __launch_bounds__(256) void k_wvt_split(const float* __restrict__ W,
                                                   unsigned short* __restrict__ Th,
                                                   unsigned short* __restrict__ Tl)
{
    __shared__ float T[64][65];
    const int tid = threadIdx.x;
    const int tx = tid & 15, ty = tid >> 4;
    const int c0 = blockIdx.x * 64;
    const int n0 = blockIdx.y * 64;
    #pragma unroll
    for (int i = 0; i < 4; ++i) {
        float4 v = *(const float4*)(W + (size_t)(c0 + ty + 16*i) * 3072 + 2048 + n0 + tx*4);
        T[ty+16*i][tx*4+0] = v.x; T[ty+16*i][tx*4+1] = v.y;
        T[ty+16*i][tx*4+2] = v.z; T[ty+16*i][tx*4+3] = v.w;
    }
    __syncthreads();
    #pragma unroll
    for (int i = 0; i < 4; ++i) {
        const int n = ty + 16*i;
        ushort4 hh, ll; unsigned short h, l;
        split1(T[tx*4+0][n], h, l); hh.x = h; ll.x = l;
        split1(T[tx*4+1][n], h, l); hh.y = h; ll.y = l;
        split1(T[tx*4+2][n], h, l); hh.z = h; ll.z = l;
        split1(T[tx*4+3][n], h, l); hh.w = h; ll.w = l;
        size_t o = (size_t)(n0 + n) * 1024 + c0 + tx*4;
        *(ushort4*)(Th + o) = hh;
        *(ushort4*)(Tl + o) = ll;
    }
}

// ---------------- elementwise fp32 -> bf16 h/l split ----------------
__global__ __launch_bounds__(256) void k_split4(const float4* __restrict__ x,
                                                ushort4* __restrict__ h4,
                                                ushort4* __restrict__ l4)
{
    const int i = blockIdx.x * 256 + threadIdx.x;
    float4 v = x[i];
    ushort4 hh, ll; unsigned short h, l;
    split1(v.x, h, l); hh.x = h; ll.x = l;
    split1(v.y, h, l); hh.y = h; ll.y = l;
    split1(v.z, h, l); hh.z = h; ll.z = l;
    split1(v.w, h, l); hh.w = h; ll.w = l;
    h4[i] = hh; l4[i] = ll;
}

// ---------------- split-bf16 MFMA NT GEMM (3-term), fp32 out with scale ----------------
__global__ __launch_bounds__(256) void k_mfma_split(
    const unsigned short* __restrict__ Ah, const unsigned short* __restrict__ Al,
    const unsigned short* __restrict__ Bh, const unsigned short* __restrict__ Bl,
    float* __restrict__ C, int N, float scale)
{
    __shared__ __align__(16) unsigned short sAh[128][32];
    __shared__ __align__(16) unsigned short sAl[128][32];
    __shared__ __align__(16) unsigned short sBh[128][32];
    __shared__ __align__(16) unsigned short sBl[128][32];
    const int tid  = threadIdx.x;
    const int lane = tid & 63;
    const int wid  = tid >> 6;
    const int wm = wid >> 1, wn = wid & 1;
    const int ar0 = blockIdx.x * 128;
    const int br0 = blockIdx.y * 128;

    f32x4 acc[4][4] = {};

    const int srow = lane >> 2;
    const int scol = (lane & 3) * 8;
    const int fr   = lane & 15;
    const int kg   = (lane >> 4) * 8;

    for (int k0 = 0; k0 < 1024; k0 += 32) {
        #pragma unroll
        for (int cc = 0; cc < 2; ++cc) {
            const int c = wid + cc * 4;
            const size_t gA = (size_t)(ar0 + c*16 + srow) * 1024 + k0 + scol;
            const size_t gB = (size_t)(br0 + c*16 + srow) * 1024 + k0 + scol;
            __builtin_amdgcn_global_load_lds((const __attribute__((address_space(1))) void*)(Ah + gA),
                (__attribute__((address_space(3))) void*)((char*)&sAh[0][0] + c*1024), 16, 0, 0);
            __builtin_amdgcn_global_load_lds((const __attribute__((address_space(1))) void*)(Al + gA),
                (__attribute__((address_space(3))) void*)((char*)&sAl[0][0] + c*1024), 16, 0, 0);
            __builtin_amdgcn_global_load_lds((const __attribute__((address_space(1))) void*)(Bh + gB),
                (__attribute__((address_space(3))) void*)((char*)&sBh[0][0] + c*1024), 16, 0, 0);
            __builtin_amdgcn_global_load_lds((const __attribute__((address_space(1))) void*)(Bl + gB),
                (__attribute__((address_space(3))) void*)((char*)&sBl[0][0] + c*1024), 16, 0, 0);
        }
        __syncthreads();

        bf16x8 aH[4], aL[4], bH[4], bL[4];
        #pragma unroll
        for (int i = 0; i < 4; ++i) {
            aH[i] = *(const bf16x8*)&sAh[wm*64 + i*16 + fr][kg];
            aL[i] = *(const bf16x8*)&sAl[wm*64 + i*16 + fr][kg];
            bH[i] = *(const bf16x8*)&sBh[wn*64 + i*16 + fr][kg];
            bL[i] = *(const bf16x8*)&sBl[wn*64 + i*16 + fr][kg];
        }
        #pragma unroll
        for (int mi = 0; mi < 4; ++mi)
            #pragma unroll
            for (int ni = 0; ni < 4; ++ni) {
                acc[mi][ni] = __builtin_amdgcn_mfma_f32_16x16x32_bf16(aH[mi], bH[ni], acc[mi][ni], 0, 0, 0);
                acc[mi][ni] = __builtin_amdgcn_mfma_f32_16x16x32_bf16(aH[mi], bL[ni], acc[mi][ni], 0, 0, 0);
                acc[mi][ni] = __builtin_amdgcn_mfma_f32_16x16x32_bf16(aL[mi], bH[ni], acc[mi][ni], 0, 0, 0);
            }
        __syncthreads();
    }

    const int rsub = (lane >> 4) * 4;
    const int csub = lane & 15;
    const int orow0 = ar0 + wm*64;
    const int ocol0 = br0 + wn*64;
    #pragma unroll
    for (int mi = 0; mi < 4; ++mi)
        #pragma unroll
        for (int ni = 0; ni < 4; ++ni)
            #pragma unroll
            for (int r = 0; r < 4; ++r)
                C[(size_t)(orow0 + mi*16 + rsub + r) * N + ocol0 + ni*16 + csub] = acc[mi][ni][r] * scale;
}

// ------------- top-24 by approx z, exact fp64 rescore, top-16 + softmax-fold + gather -------------
__global__ __launch_bounds__(256) void k_topk_out(const float* __restrict__ Z,
                                                  const float* __restrict__ V,
                                                  const double* __restrict__ Yd,
                                                  const float* __restrict__ Xo,
                                                  float* __restrict__ out)
{
    __shared__ float  zrow[SEQ];
    __shared__ double yrow[DIMD];
    __shared__ float  rvf[256];
    __shared__ int    ri[256];
    __shared__ double rvd[256];
    __shared__ double zc[NCAND];
    __shared__ int    ci[NCAND];
    __shared__ float  selw[16];
    __shared__ int    seli[16];
    __shared__ float  szmax, szsum;
    const int tid = threadIdx.x;
    const int row = blockIdx.x;

    const float* zr = Z + (size_t)row * SEQ;
    for (int i = tid; i < SEQ; i += 256) zrow[i] = zr[i];
    const double* yr = Yd + (size_t)row * DIMD;
    for (int i = tid; i < DIMD; i += 256) yrow[i] = yr[i];
    __syncthreads();

    // row max of approx z
    float mv = -3.0e38f;
    for (int i = tid; i < SEQ; i += 256) mv = fmaxf(mv, zrow[i]);
    rvf[tid] = mv; __syncthreads();
    for (int s = 128; s; s >>= 1) { if (tid < s) rvf[tid] = fmaxf(rvf[tid], rvf[tid+s]); __syncthreads(); }
    if (tid == 0) szmax = rvf[0];
    __syncthreads();
    const float zmax = szmax;

    // full softmax denominator from approx z (relative err ~1e-5, invisible)
    float ls = 0.f;
    for (int i = tid; i < SEQ; i += 256) ls += expf(zrow[i] - zmax);
    rvf[tid] = ls; __syncthreads();
    for (int s = 128; s; s >>= 1) { if (tid < s) rvf[tid] += rvf[tid+s]; __syncthreads(); }
    if (tid == 0) szsum = rvf[0];
    __syncthreads();

    // top-NCAND candidates by approx z (repeated argmax, lower-index ties)
    for (int t = 0; t < NCAND; ++t) {
        float bvv = -3.0e38f; int bii = 1 << 30;
        for (int i = tid; i < SEQ; i += 256) {
            float v = zrow[i];
            if (v > bvv || (v == bvv && i < bii)) { bvv = v; bii = i; }
        }
        rvf[tid] = bvv; ri[tid] = bii; __syncthreads();
        for (int s = 128; s; s >>= 1) {
            if (tid < s) {
                float ov = rvf[tid+s]; int oi = ri[tid+s];
                if (ov > rvf[tid] || (ov == rvf[tid] && oi < ri[tid])) { rvf[tid] = ov; ri[tid] = oi; }
            }
            __syncthreads();
        }
        if (tid == 0) { ci[t] = ri[0]; zrow[ri[0]] = -3.0e38f; }
        __syncthreads();
    }

    // EXACT rescore: zc[t] = (Y_fp64[row] . Xo[c]) / 32 in fp64
    for (int t = 0; t < NCAND; ++t) {
        const float* xc = Xo + (size_t)ci[t] * DIMD;
        double s = 0.0;
        for (int i = tid; i < DIMD; i += 256) s = fma(yrow[i], (double)xc[i], s);
        rvd[tid] = s; __syncthreads();
        for (int s2 = 128; s2; s2 >>= 1) { if (tid < s2) rvd[tid] += rvd[tid+s2]; __syncthreads(); }
        if (tid == 0) zc[t] = rvd[0] * 0.03125;
        __syncthreads();
    }

    // exact top-16 of candidates (desc value, asc index), fp64 weights
    if (tid == 0) {
        bool used[NCAND] = {};
        for (int t = 0; t < 16; ++t) {
            double bv = -1.0e300; int bj = -1;
            for (int j = 0; j < NCAND; ++j) {
                if (used[j]) continue;
                if (bj < 0 || zc[j] > bv || (zc[j] == bv && ci[j] < ci[bj])) { bv = zc[j]; bj = j; }
            }
            used[bj] = true;
            seli[t] = ci[bj];
            selw[t] = (float)exp(bv - (double)zmax);
        }
    }
    __syncthreads();

    float w[16]; int idx[16];
    #pragma unroll
    for (int j = 0; j < 16; ++j) { w[j] = selw[j]; idx[j] = seli[j]; }
    const float invZ = 1.0f / szsum;
    float* orow = out + (size_t)row * DIMD;
    for (int d = tid; d < DIMD; d += 256) {
        float acc = 0.f;
        #pragma unroll
        for (int j = 0; j < 16; ++j)
            acc = fmaf(w[j], V[(size_t)idx[j] * DIMD + d], acc);
        orow[d] = acc * invZ;
    }
}

extern "C" void kernel_launch(void* const* d_in, const int* in_sizes, int n_in,
                              void* d_out, int out_size, void* d_ws, size_t ws_size,
                              hipStream_t stream)
{
    const float* X1 = (const float*)d_in[0];
    const float* X2 = (const float*)d_in[1];
    const float* W  = (const float*)d_in[2];
    float* out = (float*)d_out;

    char* ws = (char*)d_ws;
    const size_t MB = 1ull << 20;
    double*         M   = (double*)(ws);                   //  8 MB
    unsigned short* Wvh = (unsigned short*)(ws +  8*MB);   //  2 MB
    unsigned short* Wvl = (unsigned short*)(ws + 10*MB);   //  2 MB
    unsigned short* Xsh = (unsigned short*)(ws + 12*MB);   //  4 MB (per-direction)
    unsigned short* Xsl = (unsigned short*)(ws + 16*MB);   //  4 MB
    double*         Yd  = (double*)(ws + 20*MB);           // 16 MB
    unsigned short* Yh  = (unsigned short*)(ws + 36*MB);   //  4 MB
    unsigned short* Yl  = (unsigned short*)(ws + 40*MB);   //  4 MB
    float*          V   = (float*)(ws + 36*MB);            //  8 MB (overlays Yh/Yl after Z~)
    float*          Z   = (float*)(ws + 44*MB);            // 16 MB -> peak 60 MB

    const size_t XB   = (size_t)SEQ * DIMD;
    const size_t OUTH = (size_t)8 * SEQ * DIMD;

    dim3 blk(256);
    k_gemm_m<<<dim3(16, 16), blk, 0, stream>>>(W, M);
    k_wvt_split<<<dim3(16, 16), blk, 0, stream>>>(W, Wvh, Wvl);

    for (int b = 0; b < 8; ++b) {
        const float* x1 = X1 + (size_t)b * XB;
        const float* x2 = X2 + (size_t)b * XB;

        // dir1: attn1 = softmax(q1 k2^T /32) -> out0[b] = topk(attn1) @ v2
        k_split4<<<dim3(2048), blk, 0, stream>>>((const float4*)x2, (ushort4*)Xsh, (ushort4*)Xsl);
        k_gemm_y64<<<dim3(32, 16), blk, 0, stream>>>(x1, M, Yd, Yh, Yl);
        k_mfma_split<<<dim3(16, 16), blk, 0, stream>>>(Yh, Yl, Xsh, Xsl, Z, 2048, 0.03125f);
        k_mfma_split<<<dim3(16,  8), blk, 0, stream>>>(Xsh, Xsl, Wvh, Wvl, V, 1024, 1.0f);
        k_topk_out<<<dim3(SEQ), blk, 0, stream>>>(Z, V, Yd, x2, out + (size_t)b * XB);

        // dir2: attn2 = softmax(q2 k1^T /32) -> out1[b] = topk(attn2) @ v1
        k_split4<<<dim3(2048), blk, 0, stream>>>((const float4*)x1, (ushort4*)Xsh, (ushort4*)Xsl);
        k_gemm_y64<<<dim3(32, 16), blk, 0, stream>>>(x2, M, Yd, Yh, Yl);
        k_mfma_split<<<dim3(16, 16), blk, 0, stream>>>(Yh, Yl, Xsh, Xsl, Z, 2048, 0.03125f);
        k_mfma_split<<<dim3(16,  8), blk, 0, stream>>>(Xsh, Xsl, Wvh, Wvl, V, 1024, 1.0f);
        k_topk_out<<<dim3(SEQ), blk, 0, stream>>>(Z, V, Yd, x1, out + OUTH + (size_t)b * XB);
    }
}

// Round 4
// 7542.114 us; speedup vs baseline: 1.7790x; 1.1282x over previous
//
#include <hip/hip_runtime.h>
#include <hip/hip_bf16.h>
#include <math.h>

// Bidir attention, B=8 N=2048 D=1024 topk=16. Inputs fp32, output fp32.
// Top-16 min gap over 32768 rows ~2e-6 => selection needs fp64-class logits.
// Scheme (round-3 proven, round-4 touches ONLY k_topk_out):
//   M  = Wq Wk^T        fp64 VALU GEMM (proven)
//   Y  = X  M           fp64 VALU GEMM (conflict-free microtile) + bf16 h/l split
//   Z~ = Y_split X^T/32 bf16 3-term split MFMA (fp32; zmax/denominator/candidates only)
//   V  = X Wv           bf16 3-term split MFMA (linear, tolerant)
//   topk: top-24 candidates by Z~, EXACT fp64 rescore z = Y_fp64 . X / 32,
//         exact top-16 + fp64 weights.
// Round-4: k_topk_out was barrier-bound (~430 __syncthreads/block, VALUBusy 19%,
// HBM 6%). Rewritten: z-row in registers, wave __shfl_xor reductions (1 barrier
// per candidate), rescore spread 6-candidates-per-wave with zero inner barriers.
//
// Workspace (60 MB peak):
//   M fp64        @ 0   (8 MB)  once
//   Wvh/Wvl bf16  @ 8/10 (2+2)  once
//   Xsh/Xsl bf16  @ 12/16 (4+4) per direction (split of the "other" X)
//   Yd fp64       @ 20 (16 MB)  per direction
//   Yh/Yl bf16    @ 36/40 (4+4) per direction; V fp32 (8 MB) overlays @36 after Z~
//   Z fp32        @ 44 (16 MB)

#define SEQ 2048
#define DIMD 1024
#define NCAND 24

typedef __bf16 bf16x8 __attribute__((ext_vector_type(8)));
typedef float f32x4 __attribute__((ext_vector_type(4)));

__device__ __forceinline__ void split1(float x, unsigned short& h, unsigned short& l)
{
    __hip_bfloat16 hb = __float2bfloat16(x);          // RN
    float hf = __bfloat162float(hb);
    __hip_bfloat16 lb = __float2bfloat16(x - hf);
    h = *reinterpret_cast<unsigned short*>(&hb);
    l = *reinterpret_cast<unsigned short*>(&lb);
}

// ---------------- M = Wq * Wk^T (NT, fp32 in, fp64 acc+store) — proven, untouched ----------------
__global__ __launch_bounds__(256) void k_gemm_m(const float* __restrict__ W,
                                                double* __restrict__ M)
{
    __shared__ double As[16][65];
    __shared__ double Bs[16][65];
    const int tid = threadIdx.x;
    const int tx = tid & 15, ty = tid >> 4;
    const int m0 = blockIdx.x * 64, n0 = blockIdx.y * 64;
    const int lr = tid >> 2;
    const int lk = (tid & 3) * 4;
    double acc[4][4] = {};
    for (int k0 = 0; k0 < 1024; k0 += 16) {
        float4 a = *(const float4*)(W + (size_t)(m0 + lr) * 3072 + k0 + lk);
        As[lk+0][lr] = a.x; As[lk+1][lr] = a.y; As[lk+2][lr] = a.z; As[lk+3][lr] = a.w;
        float4 b = *(const float4*)(W + (size_t)(n0 + lr) * 3072 + 1024 + k0 + lk);
        Bs[lk+0][lr] = b.x; Bs[lk+1][lr] = b.y; Bs[lk+2][lr] = b.z; Bs[lk+3][lr] = b.w;
        __syncthreads();
        #pragma unroll
        for (int kk = 0; kk < 16; ++kk) {
            double av[4], bv[4];
            #pragma unroll
            for (int i = 0; i < 4; ++i) av[i] = As[kk][ty*4+i];
            #pragma unroll
            for (int j = 0; j < 4; ++j) bv[j] = Bs[kk][tx*4+j];
            #pragma unroll
            for (int i = 0; i < 4; ++i)
                #pragma unroll
                for (int j = 0; j < 4; ++j)
                    acc[i][j] = fma(av[i], bv[j], acc[i][j]);
        }
        __syncthreads();
    }
    #pragma unroll
    for (int i = 0; i < 4; ++i)
        #pragma unroll
        for (int j = 0; j < 4; ++j)
            M[(size_t)(m0 + ty*4 + i) * 1024 + n0 + tx*4 + j] = acc[i][j];
}

// ------------- Y = X * M (NN, fp32 A, fp64 B, fp64 acc) — proven round-3, untouched ------------
__global__ __launch_bounds__(256) void k_gemm_y64(const float* __restrict__ X,
                                                  const double* __restrict__ M,
                                                  double* __restrict__ Yd,
                                                  unsigned short* __restrict__ Yh,
                                                  unsigned short* __restrict__ Yl)
{
    __shared__ double As[16][65];
    __shared__ double Bs[16][65];
    const int tid = threadIdx.x;
    const int tx = tid & 15, ty = tid >> 4;
    const int m0 = blockIdx.x * 64, n0 = blockIdx.y * 64;
    const int lr = tid >> 2;         // 0..63
    const int lk = (tid & 3) * 4;    // 0,4,8,12
    const int bk = tid >> 4;         // 0..15
    const int bn = (tid & 15) * 4;   // 0..60
    double acc[4][4] = {};
    for (int k0 = 0; k0 < 1024; k0 += 16) {
        float4 a = *(const float4*)(X + (size_t)(m0 + lr) * 1024 + k0 + lk);
        As[lk+0][lr] = a.x; As[lk+1][lr] = a.y; As[lk+2][lr] = a.z; As[lk+3][lr] = a.w;
        const double* pb = M + (size_t)(k0 + bk) * 1024 + n0 + bn;
        double2 b01 = *(const double2*)pb;
        double2 b23 = *(const double2*)(pb + 2);
        Bs[bk][bn+0] = b01.x; Bs[bk][bn+1] = b01.y; Bs[bk][bn+2] = b23.x; Bs[bk][bn+3] = b23.y;
        __syncthreads();
        #pragma unroll
        for (int kk = 0; kk < 16; ++kk) {
            double av[4], bv[4];
            #pragma unroll
            for (int i = 0; i < 4; ++i) av[i] = As[kk][ty + 16*i];   // broadcast, conflict-free
            #pragma unroll
            for (int j = 0; j < 4; ++j) bv[j] = Bs[kk][tx + 16*j];   // consecutive, conflict-free
            #pragma unroll
            for (int i = 0; i < 4; ++i)
                #pragma unroll
                for (int j = 0; j < 4; ++j)
                    acc[i][j] = fma(av[i], bv[j], acc[i][j]);
        }
        __syncthreads();
    }
    #pragma unroll
    for (int i = 0; i < 4; ++i)
        #pragma unroll
        for (int j = 0; j < 4; ++j) {
            const double y = acc[i][j];
            const size_t o = (size_t)(m0 + ty + 16*i) * 1024 + n0 + tx + 16*j;
            Yd[o] = y;
            float yf = (float)y;
            __hip_bfloat16 hb = __float2bfloat16(yf);
            float hf = __bfloat162float(hb);
            __hip_bfloat16 lb = __float2bfloat16((float)(y - (double)hf));
            Yh[o] = *reinterpret_cast<unsigned short*>(&hb);
            Yl[o] = *reinterpret_cast<unsigned short*>(&lb);
        }
}

// ---------------- Wv^T split: Th/Tl[n][c] = split(W[c][2048+n]) — untouched ----------------
__global__ __launch_bounds__(256) void k_wvt_split(const float* __restrict__ W,
                                                   unsigned short* __restrict__ Th,
                                                   unsigned short* __restrict__ Tl)
{
    __shared__ float T[64][65];
    const int tid = threadIdx.x;
    const int tx = tid & 15, ty = tid >> 4;
    const int c0 = blockIdx.x * 64;
    const int n0 = blockIdx.y * 64;
    #pragma unroll
    for (int i = 0; i < 4; ++i) {
        float4 v = *(const float4*)(W + (size_t)(c0 + ty + 16*i) * 3072 + 2048 + n0 + tx*4);
        T[ty+16*i][tx*4+0] = v.x; T[ty+16*i][tx*4+1] = v.y;
        T[ty+16*i][tx*4+2] = v.z; T[ty+16*i][tx*4+3] = v.w;
    }
    __syncthreads();
    #pragma unroll
    for (int i = 0; i < 4; ++i) {
        const int n = ty + 16*i;
        ushort4 hh, ll; unsigned short h, l;
        split1(T[tx*4+0][n], h, l); hh.x = h; ll.x = l;
        split1(T[tx*4+1][n], h, l); hh.y = h; ll.y = l;
        split1(T[tx*4+2][n], h, l); hh.z = h; ll.z = l;
        split1(T[tx*4+3][n], h, l); hh.w = h; ll.w = l;
        size_t o = (size_t)(n0 + n) * 1024 + c0 + tx*4;
        *(ushort4*)(Th + o) = hh;
        *(ushort4*)(Tl + o) = ll;
    }
}

// ---------------- elementwise fp32 -> bf16 h/l split — untouched ----------------
__global__ __launch_bounds__(256) void k_split4(const float4* __restrict__ x,
                                                ushort4* __restrict__ h4,
                                                ushort4* __restrict__ l4)
{
    const int i = blockIdx.x * 256 + threadIdx.x;
    float4 v = x[i];
    ushort4 hh, ll; unsigned short h, l;
    split1(v.x, h, l); hh.x = h; ll.x = l;
    split1(v.y, h, l); hh.y = h; ll.y = l;
    split1(v.z, h, l); hh.z = h; ll.z = l;
    split1(v.w, h, l); hh.w = h; ll.w = l;
    h4[i] = hh; l4[i] = ll;
}

// ---------------- split-bf16 MFMA NT GEMM (3-term), fp32 out with scale — untouched ----------------
__global__ __launch_bounds__(256) void k_mfma_split(
    const unsigned short* __restrict__ Ah, const unsigned short* __restrict__ Al,
    const unsigned short* __restrict__ Bh, const unsigned short* __restrict__ Bl,
    float* __restrict__ C, int N, float scale)
{
    __shared__ __align__(16) unsigned short sAh[128][32];
    __shared__ __align__(16) unsigned short sAl[128][32];
    __shared__ __align__(16) unsigned short sBh[128][32];
    __shared__ __align__(16) unsigned short sBl[128][32];
    const int tid  = threadIdx.x;
    const int lane = tid & 63;
    const int wid  = tid >> 6;
    const int wm = wid >> 1, wn = wid & 1;
    const int ar0 = blockIdx.x * 128;
    const int br0 = blockIdx.y * 128;

    f32x4 acc[4][4] = {};

    const int srow = lane >> 2;
    const int scol = (lane & 3) * 8;
    const int fr   = lane & 15;
    const int kg   = (lane >> 4) * 8;

    for (int k0 = 0; k0 < 1024; k0 += 32) {
        #pragma unroll
        for (int cc = 0; cc < 2; ++cc) {
            const int c = wid + cc * 4;
            const size_t gA = (size_t)(ar0 + c*16 + srow) * 1024 + k0 + scol;
            const size_t gB = (size_t)(br0 + c*16 + srow) * 1024 + k0 + scol;
            __builtin_amdgcn_global_load_lds((const __attribute__((address_space(1))) void*)(Ah + gA),
                (__attribute__((address_space(3))) void*)((char*)&sAh[0][0] + c*1024), 16, 0, 0);
            __builtin_amdgcn_global_load_lds((const __attribute__((address_space(1))) void*)(Al + gA),
                (__attribute__((address_space(3))) void*)((char*)&sAl[0][0] + c*1024), 16, 0, 0);
            __builtin_amdgcn_global_load_lds((const __attribute__((address_space(1))) void*)(Bh + gB),
                (__attribute__((address_space(3))) void*)((char*)&sBh[0][0] + c*1024), 16, 0, 0);
            __builtin_amdgcn_global_load_lds((const __attribute__((address_space(1))) void*)(Bl + gB),
                (__attribute__((address_space(3))) void*)((char*)&sBl[0][0] + c*1024), 16, 0, 0);
        }
        __syncthreads();

        bf16x8 aH[4], aL[4], bH[4], bL[4];
        #pragma unroll
        for (int i = 0; i < 4; ++i) {
            aH[i] = *(const bf16x8*)&sAh[wm*64 + i*16 + fr][kg];
            aL[i] = *(const bf16x8*)&sAl[wm*64 + i*16 + fr][kg];
            bH[i] = *(const bf16x8*)&sBh[wn*64 + i*16 + fr][kg];
            bL[i] = *(const bf16x8*)&sBl[wn*64 + i*16 + fr][kg];
        }
        #pragma unroll
        for (int mi = 0; mi < 4; ++mi)
            #pragma unroll
            for (int ni = 0; ni < 4; ++ni) {
                acc[mi][ni] = __builtin_amdgcn_mfma_f32_16x16x32_bf16(aH[mi], bH[ni], acc[mi][ni], 0, 0, 0);
                acc[mi][ni] = __builtin_amdgcn_mfma_f32_16x16x32_bf16(aH[mi], bL[ni], acc[mi][ni], 0, 0, 0);
                acc[mi][ni] = __builtin_amdgcn_mfma_f32_16x16x32_bf16(aL[mi], bH[ni], acc[mi][ni], 0, 0, 0);
            }
        __syncthreads();
    }

    const int rsub = (lane >> 4) * 4;
    const int csub = lane & 15;
    const int orow0 = ar0 + wm*64;
    const int ocol0 = br0 + wn*64;
    #pragma unroll
    for (int mi = 0; mi < 4; ++mi)
        #pragma unroll
        for (int ni = 0; ni < 4; ++ni)
            #pragma unroll
            for (int r = 0; r < 4; ++r)
                C[(size_t)(orow0 + mi*16 + rsub + r) * N + ocol0 + ni*16 + csub] = acc[mi][ni][r] * scale;
}

// ------------- top-24 by approx z (wave-shuffle), exact fp64 rescore (wave-parallel),
// ------------- exact top-16 + softmax-fold + gather. 1 barrier/candidate. -------------
__global__ __launch_bounds__(256) void k_topk_out(const float* __restrict__ Z,
                                                  const float* __restrict__ V,
                                                  const double* __restrict__ Yd,
                                                  const float* __restrict__ Xo,
                                                  float* __restrict__ out)
{
    __shared__ double yrow[DIMD];         // 8 KB
    __shared__ float  redv[8];
    __shared__ int    redi[8];
    __shared__ float  sums[4];
    __shared__ double zc[NCAND];
    __shared__ float  selw[16];
    __shared__ int    seli[16];
    const int tid  = threadIdx.x;
    const int lane = tid & 63;
    const int wid  = tid >> 6;
    const int row  = blockIdx.x;

    // z-row into registers: element i = tid + 256*j  (coalesced)
    const float* zr = Z + (size_t)row * SEQ;
    float zv[8];
    #pragma unroll
    for (int j = 0; j < 8; ++j) zv[j] = zr[tid + 256*j];

    // Yd row into LDS (coalesced); consumed after later barriers
    const double* yr = Yd + (size_t)row * DIMD;
    for (int i = tid; i < DIMD; i += 256) yrow[i] = yr[i];

    // local max (strict > keeps lowest index since index grows with j)
    float lmax = -3.0e38f; int lidx = 1 << 30;
    #pragma unroll
    for (int j = 0; j < 8; ++j)
        if (zv[j] > lmax) { lmax = zv[j]; lidx = tid + 256*j; }

    // ---- block max via wave shuffle + 4-leader combine ----
    {
        float v = lmax; int gi = lidx;
        #pragma unroll
        for (int off = 32; off; off >>= 1) {
            float ov = __shfl_xor(v, off);
            int   oi = __shfl_xor(gi, off);
            if (ov > v || (ov == v && oi < gi)) { v = ov; gi = oi; }
        }
        if (lane == 0) { redv[wid] = v; redi[wid] = gi; }
    }
    __syncthreads();
    float zmax;
    {
        float v = redv[0];
        #pragma unroll
        for (int w = 1; w < 4; ++w) if (redv[w] > v) v = redv[w];
        zmax = v;
    }

    // ---- full softmax denominator (pristine registers) ----
    {
        float ls = 0.f;
        #pragma unroll
        for (int j = 0; j < 8; ++j) ls += expf(zv[j] - zmax);
        #pragma unroll
        for (int off = 32; off; off >>= 1) ls += __shfl_xor(ls, off);
        if (lane == 0) sums[wid] = ls;
    }
    __syncthreads();
    const float szsum = sums[0] + sums[1] + sums[2] + sums[3];

    // ---- top-NCAND candidates: repeated wave-argmax, register removal ----
    int cand[NCAND];
    for (int t = 0; t < NCAND; ++t) {
        float v = lmax; int gi = lidx;
        #pragma unroll
        for (int off = 32; off; off >>= 1) {
            float ov = __shfl_xor(v, off);
            int   oi = __shfl_xor(gi, off);
            if (ov > v || (ov == v && oi < gi)) { v = ov; gi = oi; }
        }
        const int slot = (t & 1) * 4;
        if (lane == 0) { redv[slot + wid] = v; redi[slot + wid] = gi; }
        __syncthreads();
        {
            float bv = redv[slot]; int bi = redi[slot];
            #pragma unroll
            for (int w = 1; w < 4; ++w) {
                float ov = redv[slot + w]; int oi = redi[slot + w];
                if (ov > bv || (ov == bv && oi < bi)) { bv = ov; bi = oi; }
            }
            cand[t] = bi;
            // owner removes and recomputes its local max
            if ((bi & 255) == tid) {
                zv[bi >> 8] = -3.0e38f;
                lmax = -3.0e38f; lidx = 1 << 30;
                #pragma unroll
                for (int j = 0; j < 8; ++j)
                    if (zv[j] > lmax) { lmax = zv[j]; lidx = tid + 256*j; }
            }
        }
    }

    // ---- EXACT fp64 rescore, 6 candidates per wave, zero inner barriers ----
    // (yrow writes are ordered before the candidate-loop barriers)
    for (int s = 0; s < NCAND / 4; ++s) {
        const int t = wid + 4 * s;
        const float* xc = Xo + (size_t)cand[t] * DIMD;
        double acc = 0.0;
        #pragma unroll
        for (int e = 0; e < 16; ++e)
            acc = fma(yrow[e*64 + lane], (double)xc[e*64 + lane], acc);
        #pragma unroll
        for (int off = 32; off; off >>= 1) acc += __shfl_xor(acc, off);
        if (lane == 0) zc[t] = acc * 0.03125;
    }
    __syncthreads();

    // ---- exact top-16 of candidates (desc value, asc index), fp64 weights ----
    if (tid == 0) {
        bool used[NCAND] = {};
        for (int t = 0; t < 16; ++t) {
            double bv = -1.0e300; int bj = -1;
            for (int j = 0; j < NCAND; ++j) {
                if (used[j]) continue;
                if (bj < 0 || zc[j] > bv || (zc[j] == bv && cand[j] < cand[bj])) { bv = zc[j]; bj = j; }
            }
            used[bj] = true;
            seli[t] = cand[bj];
            selw[t] = (float)exp(bv - (double)zmax);
        }
    }
    __syncthreads();

    // ---- gather: out = sum_t w_t * V[idx_t] / denom ----
    float w[16]; int idx[16];
    #pragma unroll
    for (int j = 0; j < 16; ++j) { w[j] = selw[j]; idx[j] = seli[j]; }
    const float invZ = 1.0f / szsum;
    float* orow = out + (size_t)row * DIMD;
    #pragma unroll
    for (int jj = 0; jj < 4; ++jj) {
        const int d = tid + 256 * jj;
        float acc = 0.f;
        #pragma unroll
        for (int j = 0; j < 16; ++j)
            acc = fmaf(w[j], V[(size_t)idx[j] * DIMD + d], acc);
        orow[d] = acc * invZ;
    }
}

extern "C" void kernel_launch(void* const* d_in, const int* in_sizes, int n_in,
                              void* d_out, int out_size, void* d_ws, size_t ws_size,
                              hipStream_t stream)
{
    const float* X1 = (const float*)d_in[0];
    const float* X2 = (const float*)d_in[1];
    const float* W  = (const float*)d_in[2];
    float* out = (float*)d_out;

    char* ws = (char*)d_ws;
    const size_t MB = 1ull << 20;
    double*         M   = (double*)(ws);                   //  8 MB
    unsigned short* Wvh = (unsigned short*)(ws +  8*MB);   //  2 MB
    unsigned short* Wvl = (unsigned short*)(ws + 10*MB);   //  2 MB
    unsigned short* Xsh = (unsigned short*)(ws + 12*MB);   //  4 MB (per-direction)
    unsigned short* Xsl = (unsigned short*)(ws + 16*MB);   //  4 MB
    double*         Yd  = (double*)(ws + 20*MB);           // 16 MB
    unsigned short* Yh  = (unsigned short*)(ws + 36*MB);   //  4 MB
    unsigned short* Yl  = (unsigned short*)(ws + 40*MB);   //  4 MB
    float*          V   = (float*)(ws + 36*MB);            //  8 MB (overlays Yh/Yl after Z~)
    float*          Z   = (float*)(ws + 44*MB);            // 16 MB -> peak 60 MB

    const size_t XB   = (size_t)SEQ * DIMD;
    const size_t OUTH = (size_t)8 * SEQ * DIMD;

    dim3 blk(256);
    k_gemm_m<<<dim3(16, 16), blk, 0, stream>>>(W, M);
    k_wvt_split<<<dim3(16, 16), blk, 0, stream>>>(W, Wvh, Wvl);

    for (int b = 0; b < 8; ++b) {
        const float* x1 = X1 + (size_t)b * XB;
        const float* x2 = X2 + (size_t)b * XB;

        // dir1: attn1 = softmax(q1 k2^T /32) -> out0[b] = topk(attn1) @ v2
        k_split4<<<dim3(2048), blk, 0, stream>>>((const float4*)x2, (ushort4*)Xsh, (ushort4*)Xsl);
        k_gemm_y64<<<dim3(32, 16), blk, 0, stream>>>(x1, M, Yd, Yh, Yl);
        k_mfma_split<<<dim3(16, 16), blk, 0, stream>>>(Yh, Yl, Xsh, Xsl, Z, 2048, 0.03125f);
        k_mfma_split<<<dim3(16,  8), blk, 0, stream>>>(Xsh, Xsl, Wvh, Wvl, V, 1024, 1.0f);
        k_topk_out<<<dim3(SEQ), blk, 0, stream>>>(Z, V, Yd, x2, out + (size_t)b * XB);

        // dir2: attn2 = softmax(q2 k1^T /32) -> out1[b] = topk(attn2) @ v1
        k_split4<<<dim3(2048), blk, 0, stream>>>((const float4*)x1, (ushort4*)Xsh, (ushort4*)Xsl);
        k_gemm_y64<<<dim3(32, 16), blk, 0, stream>>>(x2, M, Yd, Yh, Yl);
        k_mfma_split<<<dim3(16, 16), blk, 0, stream>>>(Yh, Yl, Xsh, Xsl, Z, 2048, 0.03125f);
        k_mfma_split<<<dim3(16,  8), blk, 0, stream>>>(Xsh, Xsl, Wvh, Wvl, V, 1024, 1.0f);
        k_topk_out<<<dim3(SEQ), blk, 0, stream>>>(Z, V, Yd, x1, out + OUTH + (size_t)b * XB);
    }
}